// Round 6
// baseline (404.406 us; speedup 1.0000x reference)
//
#include <hip/hip_runtime.h>

typedef __bf16 bf16x8 __attribute__((ext_vector_type(8)));
typedef float  f32x4  __attribute__((ext_vector_type(4)));
typedef unsigned short u16x8 __attribute__((ext_vector_type(8)));

// Problem constants
constexpr int BB    = 16;
constexpr int TT    = 12;
constexpr int NN    = 307;
constexpr int TN    = TT * NN;        // 3684
constexpr int ROWSX = BB * TT * NN;   // 58944
constexpr int ROWSH = BB * NN;        // 4912
constexpr int SSTR  = 3840;           // xnT row stride
constexpr float SCALE = 0.125f;

__device__ __forceinline__ float wred_sum(float v) {
#pragma unroll
    for (int m = 32; m > 0; m >>= 1) v += __shfl_xor(v, m, 64);
    return v;
}

// ---------------------------------------------------------------------------
// Fold q/k projections: dg = q.k = qt.x_ + c
// ---------------------------------------------------------------------------
__global__ void fold_k(const float* __restrict__ qw, const float* __restrict__ qb,
                       const float* __restrict__ kw, const float* __restrict__ kb,
                       float* __restrict__ M, float* __restrict__ b2,
                       float* __restrict__ vv, float* __restrict__ cc) {
    int e = blockIdx.x, d = threadIdx.x;
    float acc = 0.f;
    for (int dp = 0; dp < 64; ++dp) acc += qw[dp * 64 + e] * kw[dp * 64 + d];
    M[e * 64 + d] = acc;
    float vp = wred_sum(qw[d * 64 + e] * kb[d]);
    if (d == 0) vv[e] = vp;
    if (e == 0) {
        float b = 0.f;
        for (int dp = 0; dp < 64; ++dp) b += qb[dp] * kw[dp * 64 + d];
        b2[d] = b;
        float cp = wred_sum(qb[d] * kb[d]);
        if (d == 0) *cc = cp;
    }
}

// ---------------------------------------------------------------------------
// LayerNorm -> xnb (bf16) + y32 (fp32, t==11 slab)
// ---------------------------------------------------------------------------
__global__ __launch_bounds__(256) void ln_k(const float* __restrict__ x,
                                            const float* __restrict__ g,
                                            const float* __restrict__ b,
                                            __bf16* __restrict__ xnb,
                                            float* __restrict__ y32) {
    int w = threadIdx.x >> 6, l = threadIdx.x & 63;
    int r = blockIdx.x * 4 + w;
    if (r >= ROWSX) return;
    float val = x[r * 64 + l];
    float mu  = wred_sum(val) * (1.f / 64.f);
    float dv  = val - mu;
    float var = wred_sum(dv * dv) * (1.f / 64.f);
    float xv  = dv * rsqrtf(var + 1e-5f) * g[l] + b[l];
    xnb[(size_t)r * 64 + l] = (__bf16)xv;
    int t = (r / NN) % TT;
    if (t == TT - 1) {
        int bbv = r / (NN * TT), n = r % NN;
        y32[(bbv * NN + n) * 64 + l] = xv;
    }
}

// ---------------------------------------------------------------------------
// Transpose xnb[b,j,d] -> xnT[b,d,j] (stride SSTR; j>=TN zero within tiles)
// ---------------------------------------------------------------------------
__global__ __launch_bounds__(256) void t_k(const __bf16* __restrict__ xnb,
                                           __bf16* __restrict__ xnT) {
    __shared__ unsigned short tile[64][65];
    int bb = blockIdx.y, j0 = blockIdx.x * 64, t = threadIdx.x;
    const unsigned short* src = (const unsigned short*)xnb;
    unsigned short* dst = (unsigned short*)xnT;
#pragma unroll
    for (int i = 0; i < 16; ++i) {
        int f = t + 256 * i, jr = f >> 6, dc = f & 63;
        int j = j0 + jr;
        tile[jr][dc] = (j < TN) ? src[((size_t)bb * TN + j) * 64 + dc] : (unsigned short)0;
    }
    __syncthreads();
#pragma unroll
    for (int i = 0; i < 16; ++i) {
        int f = t + 256 * i, d = f >> 6, jj = f & 63;
        dst[((size_t)bb * 64 + d) * SSTR + j0 + jj] = tile[jj][d];
    }
}

// ---------------------------------------------------------------------------
// qt[row] = y_ @ M + b2 (bf16);  cq[row] = y_.v + cc
// ---------------------------------------------------------------------------
__global__ __launch_bounds__(256) void qt_k(const float* __restrict__ y32,
                                            const float* __restrict__ M,
                                            const float* __restrict__ b2,
                                            const float* __restrict__ vv,
                                            const float* __restrict__ ccp,
                                            __bf16* __restrict__ qtb,
                                            float* __restrict__ cq) {
    int w = threadIdx.x >> 6, l = threadIdx.x & 63;
    int rr = blockIdx.x * 4 + w;
    if (rr >= ROWSH) return;
    float y = y32[rr * 64 + l];
    float acc = b2[l];
#pragma unroll
    for (int e = 0; e < 64; ++e) acc += __shfl(y, e, 64) * M[e * 64 + l];
    qtb[(size_t)rr * 64 + l] = (__bf16)acc;
    float cp = wred_sum(y * vv[l]);
    if (l == 0) cq[rr] = cp + *ccp;
}

// ---------------------------------------------------------------------------
// Fully fused: QK MFMA + sigmoid*stg*scale -> LDS (sag never hits global),
// exact top-k threshold (binary search over bf16 keys, registers+shuffles),
// softmax, PV MFMA, residual. 4 n-rows per block, one row per wave.
// LDS 33.9 KB -> 4 blocks/CU.
// ---------------------------------------------------------------------------
__global__ __launch_bounds__(256) void fat_k(const __bf16* __restrict__ qtb,
                                             const float* __restrict__ cq,
                                             const __bf16* __restrict__ xnb,
                                             const float* __restrict__ stg,
                                             const __bf16* __restrict__ xnT,
                                             const float* __restrict__ y32,
                                             const int* __restrict__ topk_p,
                                             float* __restrict__ h) {
    __shared__ unsigned short sg[4][3720];   // 29.76 KB (bf16 weights)
    __shared__ float red[4][4][64];          // 4 KB
    int t = threadIdx.x;
    int bb = blockIdx.y, n0 = blockIdx.x * 4;
    int wid = t >> 6, lane = t & 63;
    int m16 = lane & 15, q4 = lane >> 4;

    // ---------- QK + epilogue -> sg ----------
    int arow = bb * NN + min(n0 + m16, NN - 1);   // rows 4..15 don't-care
    const bf16x8* ap = (const bf16x8*)(qtb + (size_t)arow * 64);
    bf16x8 a0 = ap[q4], a1 = ap[q4 + 4];
    float cn[4];
#pragma unroll
    for (int r = 0; r < 4; ++r) {
        int n = n0 + r;
        cn[r] = (n < NN) ? cq[bb * NN + n] : 0.f;
    }
    const size_t xb = (size_t)bb * TN;
    for (int i = 0; i < 58; ++i) {            // 232 j-tiles of 16, 58/wave
        int jt = wid * 58 + i;
        int j0t = jt * 16;
        int brow = min(j0t + m16, TN - 1);    // clamp: cols j>=TN zeroed below
        const bf16x8* bp = (const bf16x8*)(xnb + (xb + brow) * 64);
        bf16x8 b0 = bp[q4], b1 = bp[q4 + 4];
        f32x4 c = {0.f, 0.f, 0.f, 0.f};
        c = __builtin_amdgcn_mfma_f32_16x16x32_bf16(a0, b0, c, 0, 0, 0);
        c = __builtin_amdgcn_mfma_f32_16x16x32_bf16(a1, b1, c, 0, 0, 0);
        if (q4 == 0) {                        // C rows 0..3 live in quad 0
            int j = j0t + m16;
            bool jv = (j < TN);
            float sv[4];
#pragma unroll
            for (int r = 0; r < 4; ++r) {
                int n = n0 + r;
                sv[r] = (jv && n < NN) ? stg[((size_t)(bb * NN + n)) * TN + j] : 0.f;
            }
#pragma unroll
            for (int r = 0; r < 4; ++r) {
                float dg = (c[r] + cn[r]) * SCALE;
                float s  = 1.f / (1.f + __expf(-dg));
                float wv = jv ? s * sv[r] * SCALE : 0.f;
                __bf16 wb = (__bf16)wv;
                sg[r][j] = *(unsigned short*)&wb;   // pads j in [TN,3712) get 0
            }
        }
    }
    __syncthreads();

    // ---------- per-wave: row wid — top-k threshold + softmax ----------
    int topkv = *topk_p;
    bool selAll = (topkv <= 0);
    int kk = 0;
    if (!selAll) {
        kk = (topkv < 5) ? topkv * NN : topkv;
        if (kk > TN) kk = TN;
    }
    u16x8 va[8];
#pragma unroll
    for (int ci = 0; ci < 8; ++ci) {
        int c = lane + (ci << 6);
        u16x8 v = {0, 0, 0, 0, 0, 0, 0, 0};
        if (c < 464) v = *(const u16x8*)&sg[wid][c * 8];
        va[ci] = v;
    }
    int vmb = 0;
#pragma unroll
    for (int ci = 0; ci < 8; ++ci)
#pragma unroll
        for (int e = 0; e < 8; ++e) vmb = max(vmb, (int)va[ci][e]);
#pragma unroll
    for (int m = 32; m > 0; m >>= 1) vmb = max(vmb, __shfl_xor(vmb, m, 64));
    float vmax = __uint_as_float(((unsigned)vmb) << 16);

    unsigned thrb = 0;
    if (!selAll) {
        unsigned lo = 0, hi = (unsigned)vmb;   // answer in [0, rowmax]
        while (lo < hi) {
            unsigned mid = (lo + hi) >> 1;
            int cnt = 0;
#pragma unroll
            for (int ci = 0; ci < 8; ++ci)
#pragma unroll
                for (int e = 0; e < 8; ++e) cnt += ((unsigned)va[ci][e] > mid);
#pragma unroll
            for (int m = 32; m > 0; m >>= 1) cnt += __shfl_xor(cnt, m, 64);
            if (cnt < kk) hi = mid; else lo = mid + 1;
        }
        thrb = lo;   // bits of the kk-th largest bf16 value
    }

    float local = 0.f;
#pragma unroll
    for (int ci = 0; ci < 8; ++ci) {
        int c = lane + (ci << 6);
        int nvv = (c < 460) ? 8 : ((c == 460) ? 4 : 0);
#pragma unroll
        for (int e = 0; e < 8; ++e) {
            unsigned u = va[ci][e];
            bool sel = selAll ? (e < nvv) : (u > thrb);
            float ev = sel ? __expf(__uint_as_float(u << 16) - vmax) : 0.f;
            local += ev;
            __bf16 eb = (__bf16)ev;
            va[ci][e] = *(unsigned short*)&eb;
        }
    }
    local = wred_sum(local);
    bool uni = !(local > 0.f);
    float inv = uni ? 0.f : 1.f / local;
    float uval = 1.f / (float)TN;
#pragma unroll
    for (int ci = 0; ci < 8; ++ci) {
        int c = lane + (ci << 6);
        if (c < 464) {
            int nvv = (c < 460) ? 8 : ((c == 460) ? 4 : 0);
            bf16x8 o;
#pragma unroll
            for (int e = 0; e < 8; ++e) {
                if (uni) o[e] = (e < nvv) ? (__bf16)uval : (__bf16)0.f;
                else {
                    unsigned short us = va[ci][e];
                    float ev = (float)(*(__bf16*)&us);
                    o[e] = (__bf16)(ev * inv);
                }
            }
            *(bf16x8*)&sg[wid][c * 8] = o;
        }
    }
    __syncthreads();

    // ---------- PV: rows 0..3, K=3712 split 4 waves x 928 ----------
    bf16x8 zf;
#pragma unroll
    for (int e = 0; e < 8; ++e) zf[e] = (__bf16)0.f;
    f32x4 acc[4];
#pragma unroll
    for (int dt = 0; dt < 4; ++dt) acc[dt] = (f32x4){0.f, 0.f, 0.f, 0.f};
    const __bf16* bbase = xnT + (size_t)bb * 64 * SSTR;
    int kbase = wid * 928;
    for (int ks = 0; ks < 29; ++ks) {
        int k0 = kbase + ks * 32 + q4 * 8;
        bf16x8 a = (m16 < 4) ? *(const bf16x8*)&sg[m16][k0] : zf;
#pragma unroll
        for (int dt = 0; dt < 4; ++dt) {
            bf16x8 b = *(const bf16x8*)(bbase + (size_t)(dt * 16 + m16) * SSTR + k0);
            acc[dt] = __builtin_amdgcn_mfma_f32_16x16x32_bf16(a, b, acc[dt], 0, 0, 0);
        }
    }
    if (q4 == 0) {   // C rows 0..3 live in quad 0, regs 0..3
#pragma unroll
        for (int dt = 0; dt < 4; ++dt)
#pragma unroll
            for (int r2 = 0; r2 < 4; ++r2)
                red[wid][r2][dt * 16 + m16] = acc[dt][r2];
    }
    __syncthreads();

    // ---------- cross-wave reduce + residual ----------
    int nn2 = n0 + wid;          // one row per wave, one col per lane
    if (nn2 < NN) {
        float s = red[0][wid][lane] + red[1][wid][lane] +
                  red[2][wid][lane] + red[3][wid][lane];
        size_t o = (size_t)(bb * NN + nn2) * 64 + lane;
        h[o] = s + y32[o];
    }
}

// ---------------------------------------------------------------------------
// FFN: out = h + (relu(LN(h)@fc1^T + b1)@fc2^T + b2)    16 rows/block
// ---------------------------------------------------------------------------
__global__ __launch_bounds__(256) void ffn_k(const float* __restrict__ h,
                                             const float* __restrict__ g,
                                             const float* __restrict__ bln,
                                             const float* __restrict__ fc1w,
                                             const float* __restrict__ fc1b,
                                             const float* __restrict__ fc2w,
                                             const float* __restrict__ fc2b,
                                             float* __restrict__ out) {
    __shared__ float zbuf[16 * 65];
    __shared__ float wbuf[256 * 65];
    __shared__ float abuf[16 * 257];
    int t = threadIdx.x;
    int r0 = blockIdx.x * 16;
    int w = t >> 6, l = t & 63;
    for (int q = 0; q < 4; ++q) {
        int rloc = w * 4 + q;
        float val = h[(r0 + rloc) * 64 + l];
        float mu  = wred_sum(val) * (1.f / 64.f);
        float dv  = val - mu;
        float var = wred_sum(dv * dv) * (1.f / 64.f);
        zbuf[rloc * 65 + l] = dv * rsqrtf(var + 1e-5f) * g[l] + bln[l];
    }
#pragma unroll
    for (int i = 0; i < 64; ++i) {
        int f = t + 256 * i, row = f >> 6, col = f & 63;
        wbuf[row * 65 + col] = fc1w[f];
    }
    __syncthreads();
    {
        int tr = t >> 6, tc = t & 63;
        float acc[4][4];
#pragma unroll
        for (int a = 0; a < 4; ++a)
#pragma unroll
            for (int c = 0; c < 4; ++c) acc[a][c] = 0.f;
#pragma unroll 4
        for (int d = 0; d < 64; ++d) {
            float av[4], bv[4];
#pragma unroll
            for (int ri = 0; ri < 4; ++ri) av[ri] = zbuf[(tr + 4 * ri) * 65 + d];
#pragma unroll
            for (int ci = 0; ci < 4; ++ci) bv[ci] = wbuf[(tc + 64 * ci) * 65 + d];
#pragma unroll
            for (int ri = 0; ri < 4; ++ri)
#pragma unroll
                for (int ci = 0; ci < 4; ++ci) acc[ri][ci] += av[ri] * bv[ci];
        }
#pragma unroll
        for (int ri = 0; ri < 4; ++ri)
#pragma unroll
            for (int ci = 0; ci < 4; ++ci) {
                int i = tc + 64 * ci;
                abuf[(tr + 4 * ri) * 257 + i] = fmaxf(acc[ri][ci] + fc1b[i], 0.f);
            }
    }
    __syncthreads();
#pragma unroll
    for (int i = 0; i < 64; ++i) {
        int f = t + 256 * i, row = f >> 8, col = f & 255;
        wbuf[row * 257 + col] = fc2w[f];
    }
    __syncthreads();
    {
        int tg = t >> 4, tc4 = t & 15;
        float acc2[4] = {0.f, 0.f, 0.f, 0.f};
#pragma unroll 8
        for (int k = 0; k < 256; ++k) {
            float a = abuf[tg * 257 + k];
#pragma unroll
            for (int ci = 0; ci < 4; ++ci) acc2[ci] += a * wbuf[(tc4 + 16 * ci) * 257 + k];
        }
#pragma unroll
        for (int ci = 0; ci < 4; ++ci) {
            int c = tc4 + 16 * ci;
            int row = r0 + tg;
            out[row * 64 + c] = h[row * 64 + c] + acc2[ci] + fc2b[c];
        }
    }
}

extern "C" void kernel_launch(void* const* d_in, const int* in_sizes, int n_in,
                              void* d_out, int out_size, void* d_ws, size_t ws_size,
                              hipStream_t stream) {
    const float* x    = (const float*)d_in[0];
    const float* stg  = (const float*)d_in[1];
    const int*   topk = (const int*)d_in[2];
    const float* qw   = (const float*)d_in[3];
    const float* qb   = (const float*)d_in[4];
    const float* kw   = (const float*)d_in[5];
    const float* kb   = (const float*)d_in[6];
    const float* lng  = (const float*)d_in[7];
    const float* lnb  = (const float*)d_in[8];
    const float* flng = (const float*)d_in[9];
    const float* flnb = (const float*)d_in[10];
    const float* fc1w = (const float*)d_in[11];
    const float* fc1b = (const float*)d_in[12];
    const float* fc2w = (const float*)d_in[13];
    const float* fc2b = (const float*)d_in[14];
    float* out = (float*)d_out;

    // Workspace layout (float units), ~19 MB total (sag eliminated)
    float* ws = (float*)d_ws;
    __bf16* xnb = (__bf16*)ws;                 // ROWSX*64 bf16 = 1,886,208 f
    float* p1   = ws + 1886208;
    __bf16* xnT = (__bf16*)p1;                 // 16*64*3840 bf16 = 1,966,080 f
    float* p2   = p1 + 1966080;
    __bf16* qtb = (__bf16*)p2;                 // 4928*64 bf16 = 157,696 f
    float* y32  = p2 + 157696;                 // 314,368 f
    float* cq   = y32 + 314368;                // 4,928 f
    float* M    = cq + 4928;                   // 4,096
    float* b2   = M + 4096;                    // 64
    float* vv   = b2 + 64;                     // 64
    float* cc   = vv + 64;                     // 16
    float* h    = cc + 16;                     // 314,368 f

    fold_k<<<64, 64, 0, stream>>>(qw, qb, kw, kb, M, b2, vv, cc);
    ln_k<<<(ROWSX + 3) / 4, 256, 0, stream>>>(x, lng, lnb, xnb, y32);
    t_k<<<dim3((TN + 63) / 64, BB), 256, 0, stream>>>(xnb, xnT);
    qt_k<<<(ROWSH + 3) / 4, 256, 0, stream>>>(y32, M, b2, vv, cc, qtb, cq);
    fat_k<<<dim3((NN + 3) / 4, BB), 256, 0, stream>>>(qtb, cq, xnb, stg, xnT, y32, topk, h);
    ffn_k<<<ROWSH / 16, 256, 0, stream>>>(h, flng, flnb, fc1w, fc1b, fc2w, fc2b, out);
}

// Round 7
// 296.398 us; speedup vs baseline: 1.3644x; 1.3644x over previous
//
#include <hip/hip_runtime.h>

typedef __bf16 bf16x8 __attribute__((ext_vector_type(8)));
typedef float  f32x4  __attribute__((ext_vector_type(4)));
typedef unsigned short u16x8 __attribute__((ext_vector_type(8)));

// Problem constants
constexpr int BB    = 16;
constexpr int TT    = 12;
constexpr int NN    = 307;
constexpr int TN    = TT * NN;        // 3684
constexpr int ROWSX = BB * TT * NN;   // 58944
constexpr int ROWSH = BB * NN;        // 4912
constexpr int SST1  = 3712;           // sag row stride (464 x b128 chunks)
constexpr int SSTR  = 3840;           // xnT row stride
constexpr float SCALE = 0.125f;

__device__ __forceinline__ float wred_sum(float v) {
#pragma unroll
    for (int m = 32; m > 0; m >>= 1) v += __shfl_xor(v, m, 64);
    return v;
}

// ---------------------------------------------------------------------------
// Fold q/k projections: dg = q.k = qt.x_ + c
// ---------------------------------------------------------------------------
__global__ void fold_k(const float* __restrict__ qw, const float* __restrict__ qb,
                       const float* __restrict__ kw, const float* __restrict__ kb,
                       float* __restrict__ M, float* __restrict__ b2,
                       float* __restrict__ vv, float* __restrict__ cc) {
    int e = blockIdx.x, d = threadIdx.x;
    float acc = 0.f;
    for (int dp = 0; dp < 64; ++dp) acc += qw[dp * 64 + e] * kw[dp * 64 + d];
    M[e * 64 + d] = acc;
    float vp = wred_sum(qw[d * 64 + e] * kb[d]);
    if (d == 0) vv[e] = vp;
    if (e == 0) {
        float b = 0.f;
        for (int dp = 0; dp < 64; ++dp) b += qb[dp] * kw[dp * 64 + d];
        b2[d] = b;
        float cp = wred_sum(qb[d] * kb[d]);
        if (d == 0) *cc = cp;
    }
}

// ---------------------------------------------------------------------------
// fc1w/fc2w fp32 -> bf16 (layouts already k-contiguous for MFMA B-fragments)
// ---------------------------------------------------------------------------
__global__ void wconv_k(const float* __restrict__ fc1w, const float* __restrict__ fc2w,
                        __bf16* __restrict__ fc1b16, __bf16* __restrict__ fc2b16) {
    int i = blockIdx.x * 256 + threadIdx.x;
    if (i < 16384) fc1b16[i] = (__bf16)fc1w[i];
    else fc2b16[i - 16384] = (__bf16)fc2w[i - 16384];
}

// ---------------------------------------------------------------------------
// LayerNorm -> xnb (bf16) + y32 (fp32, t==11 slab)
// ---------------------------------------------------------------------------
__global__ __launch_bounds__(256) void ln_k(const float* __restrict__ x,
                                            const float* __restrict__ g,
                                            const float* __restrict__ b,
                                            __bf16* __restrict__ xnb,
                                            float* __restrict__ y32) {
    int w = threadIdx.x >> 6, l = threadIdx.x & 63;
    int r = blockIdx.x * 4 + w;
    if (r >= ROWSX) return;
    float val = x[r * 64 + l];
    float mu  = wred_sum(val) * (1.f / 64.f);
    float dv  = val - mu;
    float var = wred_sum(dv * dv) * (1.f / 64.f);
    float xv  = dv * rsqrtf(var + 1e-5f) * g[l] + b[l];
    xnb[(size_t)r * 64 + l] = (__bf16)xv;
    int t = (r / NN) % TT;
    if (t == TT - 1) {
        int bbv = r / (NN * TT), n = r % NN;
        y32[(bbv * NN + n) * 64 + l] = xv;
    }
}

// ---------------------------------------------------------------------------
// Transpose xnb[b,j,d] -> xnT[b,d,j] (stride SSTR; j>=TN zero within tiles)
// ---------------------------------------------------------------------------
__global__ __launch_bounds__(256) void t_k(const __bf16* __restrict__ xnb,
                                           __bf16* __restrict__ xnT) {
    __shared__ unsigned short tile[64][65];
    int bb = blockIdx.y, j0 = blockIdx.x * 64, t = threadIdx.x;
    const unsigned short* src = (const unsigned short*)xnb;
    unsigned short* dst = (unsigned short*)xnT;
#pragma unroll
    for (int i = 0; i < 16; ++i) {
        int f = t + 256 * i, jr = f >> 6, dc = f & 63;
        int j = j0 + jr;
        tile[jr][dc] = (j < TN) ? src[((size_t)bb * TN + j) * 64 + dc] : (unsigned short)0;
    }
    __syncthreads();
#pragma unroll
    for (int i = 0; i < 16; ++i) {
        int f = t + 256 * i, d = f >> 6, jj = f & 63;
        dst[((size_t)bb * 64 + d) * SSTR + j0 + jj] = tile[jj][d];
    }
}

// ---------------------------------------------------------------------------
// qt[row] = y_ @ M + b2 (bf16);  cq[row] = y_.v + cc
// ---------------------------------------------------------------------------
__global__ __launch_bounds__(256) void qt_k(const float* __restrict__ y32,
                                            const float* __restrict__ M,
                                            const float* __restrict__ b2,
                                            const float* __restrict__ vv,
                                            const float* __restrict__ ccp,
                                            __bf16* __restrict__ qtb,
                                            float* __restrict__ cq) {
    int w = threadIdx.x >> 6, l = threadIdx.x & 63;
    int rr = blockIdx.x * 4 + w;
    if (rr >= ROWSH) return;
    float y = y32[rr * 64 + l];
    float acc = b2[l];
#pragma unroll
    for (int e = 0; e < 64; ++e) acc += __shfl(y, e, 64) * M[e * 64 + l];
    qtb[(size_t)rr * 64 + l] = (__bf16)acc;
    float cp = wred_sum(y * vv[l]);
    if (l == 0) cq[rr] = cp + *ccp;
}

// ---------------------------------------------------------------------------
// Score GEMM via MFMA. stg tile staged LDS via coalesced float4 (latency
// overlapped with MFMA). Writes sag row stride SST1, zeros for j>=TN.
// ---------------------------------------------------------------------------
__global__ __launch_bounds__(256) void score_k(const __bf16* __restrict__ qtb,
                                               const float* __restrict__ cq,
                                               const __bf16* __restrict__ xnb,
                                               const float* __restrict__ stg,
                                               __bf16* __restrict__ sag) {
    __shared__ float sstg[64 * 132];   // 33 KB, stride 132 breaks conflicts
    int bb = blockIdx.z, n0 = blockIdx.y * 64, j0 = blockIdx.x * 128;
    int t = threadIdx.x;
    int w = t >> 6, lane = t & 63;
    int m16 = lane & 15, q4 = lane >> 4;

    // ---- stage stg tile [64n x 128j] fp32 -> LDS (coalesced float4) ----
#pragma unroll
    for (int i = 0; i < 8; ++i) {
        int flat = t + i * 256;            // 0..2047
        int row = flat >> 5, c4 = (flat & 31) * 4;
        int n = n0 + row;
        float4 v = {0.f, 0.f, 0.f, 0.f};
        if (n < NN) {
            size_t rb = (size_t)(bb * NN + n) * TN;
            int j = j0 + c4;
            if (j + 3 < TN) v = *(const float4*)(stg + rb + j);
            else {
                if (j + 0 < TN) v.x = stg[rb + j + 0];
                if (j + 1 < TN) v.y = stg[rb + j + 1];
                if (j + 2 < TN) v.z = stg[rb + j + 2];
                if (j + 3 < TN) v.w = stg[rb + j + 3];
            }
        }
        *(float4*)&sstg[row * 132 + c4] = v;
    }

    // ---- MFMA: 64n x 128j, K=64 ----
    const bf16x8* ap = (const bf16x8*)(qtb + ((size_t)bb * NN + n0 + w * 16 + m16) * 64);
    bf16x8 a0 = ap[q4], a1 = ap[q4 + 4];
    f32x4 acc[8];
#pragma unroll
    for (int jt = 0; jt < 8; ++jt) {
        const bf16x8* bp = (const bf16x8*)(xnb + ((size_t)bb * TN + j0 + jt * 16 + m16) * 64);
        bf16x8 b0 = bp[q4], b1 = bp[q4 + 4];
        f32x4 c = {0.f, 0.f, 0.f, 0.f};
        c = __builtin_amdgcn_mfma_f32_16x16x32_bf16(a0, b0, c, 0, 0, 0);
        c = __builtin_amdgcn_mfma_f32_16x16x32_bf16(a1, b1, c, 0, 0, 0);
        acc[jt] = c;
    }
    int nbase = n0 + w * 16 + q4 * 4;
    float cn[4];
#pragma unroll
    for (int r = 0; r < 4; ++r) {
        int n = nbase + r;
        cn[r] = (n < NN) ? cq[bb * NN + n] : 0.f;
    }
    __syncthreads();

    // ---- epilogue: sigmoid * stg * scale ----
#pragma unroll
    for (int r = 0; r < 4; ++r) {
        int n = nbase + r;
        if (n >= NN) continue;
        int nloc = w * 16 + q4 * 4 + r;
        size_t rb = ((size_t)bb * NN + n) * SST1;
#pragma unroll
        for (int jt = 0; jt < 8; ++jt) {
            int j = j0 + jt * 16 + m16;
            float sv = sstg[nloc * 132 + jt * 16 + m16];
            float dg = (acc[jt][r] + cn[r]) * SCALE;
            float s  = 1.f / (1.f + __expf(-dg));
            float wv = (j < TN) ? s * sv * SCALE : 0.f;
            sag[rb + j] = (__bf16)wv;
        }
    }
}

// ---------------------------------------------------------------------------
// attn v2: 4 rows/block, ONE row per wave (topk+softmax in registers,
// exact binary-search threshold), weights -> LDS (30 KB -> ~5 blocks/CU),
// PV d-split across waves (no cross-wave reduce), residual, write h.
// ---------------------------------------------------------------------------
__global__ __launch_bounds__(256) void attn_k(const __bf16* __restrict__ sagB,
                                              const __bf16* __restrict__ xnT,
                                              const float* __restrict__ y32,
                                              const int* __restrict__ topk_p,
                                              float* __restrict__ h) {
    __shared__ unsigned short sg[4][3720];   // 29.76 KB
    int t = threadIdx.x;
    int bb = blockIdx.y, n0 = blockIdx.x * 4;
    int wid = t >> 6, lane = t & 63;
    int m16 = lane & 15, q4 = lane >> 4;

    int topkv = *topk_p;
    bool selAll = (topkv <= 0);
    int kk = 0;
    if (!selAll) {
        kk = (topkv < 5) ? topkv * NN : topkv;
        if (kk > TN) kk = TN;
    }

    // ---- wave wid owns row n0+wid: load raw sag to registers ----
    int n = n0 + wid;
    const u16x8* src = (const u16x8*)((const unsigned short*)sagB +
                                      (size_t)(bb * NN + min(n, NN - 1)) * SST1);
    u16x8 va[8];
#pragma unroll
    for (int ci = 0; ci < 8; ++ci) {
        int c = lane + (ci << 6);
        u16x8 v = {0, 0, 0, 0, 0, 0, 0, 0};
        if (c < 464) v = src[c];
        va[ci] = v;
    }
    // row max (values >= 0: bf16 bit order = value order; pads are 0)
    int vmb = 0;
#pragma unroll
    for (int ci = 0; ci < 8; ++ci)
#pragma unroll
        for (int e = 0; e < 8; ++e) vmb = max(vmb, (int)va[ci][e]);
#pragma unroll
    for (int m = 32; m > 0; m >>= 1) vmb = max(vmb, __shfl_xor(vmb, m, 64));
    float vmax = __uint_as_float(((unsigned)vmb) << 16);

    // exact kk-th largest via binary search: smallest T with cnt(>T) < kk
    unsigned thrb = 0;
    if (!selAll) {
        unsigned lo = 0, hi = (unsigned)vmb;
        while (lo < hi) {
            unsigned mid = (lo + hi) >> 1;
            int cnt = 0;
#pragma unroll
            for (int ci = 0; ci < 8; ++ci)
#pragma unroll
                for (int e = 0; e < 8; ++e) cnt += ((unsigned)va[ci][e] > mid);
#pragma unroll
            for (int m = 32; m > 0; m >>= 1) cnt += __shfl_xor(cnt, m, 64);
            if (cnt < kk) hi = mid; else lo = mid + 1;
        }
        thrb = lo;
    }

    // softmax sum over selected (cache exp as bf16 in-place)
    float local = 0.f;
#pragma unroll
    for (int ci = 0; ci < 8; ++ci) {
        int c = lane + (ci << 6);
        int nvv = (c < 460) ? 8 : ((c == 460) ? 4 : 0);
#pragma unroll
        for (int e = 0; e < 8; ++e) {
            unsigned u = va[ci][e];
            bool sel = selAll ? (e < nvv) : (u > thrb);
            float ev = sel ? __expf(__uint_as_float(u << 16) - vmax) : 0.f;
            local += ev;
            __bf16 eb = (__bf16)ev;
            va[ci][e] = *(unsigned short*)&eb;
        }
    }
    local = wred_sum(local);
    bool uni = !(local > 0.f);
    float inv = uni ? 0.f : 1.f / local;
    float uval = 1.f / (float)TN;
    // normalize + write weights to LDS (bf16)
#pragma unroll
    for (int ci = 0; ci < 8; ++ci) {
        int c = lane + (ci << 6);
        if (c < 464) {
            int nvv = (c < 460) ? 8 : ((c == 460) ? 4 : 0);
            bf16x8 o;
#pragma unroll
            for (int e = 0; e < 8; ++e) {
                if (uni) o[e] = (e < nvv) ? (__bf16)uval : (__bf16)0.f;
                else {
                    unsigned short us = va[ci][e];
                    float ev = (float)(*(__bf16*)&us);
                    o[e] = (__bf16)(ev * inv);
                }
            }
            *(bf16x8*)&sg[wid][c * 8] = o;
        }
    }
    __syncthreads();

    // ---- PV, d-split: wave wid owns d-cols 16*wid..16*wid+15, full K ----
    bf16x8 zf;
#pragma unroll
    for (int e = 0; e < 8; ++e) zf[e] = (__bf16)0.f;
    f32x4 acc0 = {0.f, 0.f, 0.f, 0.f}, acc1 = {0.f, 0.f, 0.f, 0.f};
    const __bf16* bbase = xnT + ((size_t)bb * 64 + wid * 16 + m16) * SSTR + q4 * 8;
    for (int ks = 0; ks < 116; ks += 2) {
        int k0 = ks * 32, k1 = k0 + 32;
        bf16x8 a0 = (m16 < 4) ? *(const bf16x8*)&sg[m16][k0 + q4 * 8] : zf;
        bf16x8 a1 = (m16 < 4) ? *(const bf16x8*)&sg[m16][k1 + q4 * 8] : zf;
        bf16x8 b0 = *(const bf16x8*)(bbase + k0);
        bf16x8 b1 = *(const bf16x8*)(bbase + k1);
        acc0 = __builtin_amdgcn_mfma_f32_16x16x32_bf16(a0, b0, acc0, 0, 0, 0);
        acc1 = __builtin_amdgcn_mfma_f32_16x16x32_bf16(a1, b1, acc1, 0, 0, 0);
    }
    if (q4 == 0) {   // C rows 0..3 live in quad 0, regs 0..3
#pragma unroll
        for (int r = 0; r < 4; ++r) {
            int nn2 = n0 + r;
            if (nn2 < NN) {
                size_t o = (size_t)(bb * NN + nn2) * 64 + wid * 16 + m16;
                h[o] = acc0[r] + acc1[r] + y32[o];
            }
        }
    }
}

// ---------------------------------------------------------------------------
// FFN v2 via MFMA bf16: LN -> zb16(LDS) -> @fc1^T+relu -> ab16(LDS)
// -> @fc2^T + h + b. 16 rows/block, LDS ~11 KB, weights from L2 (bf16).
// ---------------------------------------------------------------------------
__global__ __launch_bounds__(256) void ffn_k(const float* __restrict__ h,
                                             const float* __restrict__ g,
                                             const float* __restrict__ bln,
                                             const __bf16* __restrict__ fc1b16,
                                             const float* __restrict__ fc1b,
                                             const __bf16* __restrict__ fc2b16,
                                             const float* __restrict__ fc2b,
                                             float* __restrict__ out) {
    __shared__ __bf16 zb[16 * 68];     // A-tile GEMM1 (stride 68: conflict-lite)
    __shared__ __bf16 ab[16 * 264];    // A-tile GEMM2 (stride 264)
    int t = threadIdx.x, r0 = blockIdx.x * 16;
    int wid = t >> 6, lane = t & 63;
    int m16 = lane & 15, q4 = lane >> 4;

    // ---- LN: wave wid does rows wid*4..wid*4+3 ----
#pragma unroll
    for (int q = 0; q < 4; ++q) {
        int rl = wid * 4 + q;
        float val = h[(size_t)(r0 + rl) * 64 + lane];
        float mu  = wred_sum(val) * (1.f / 64.f);
        float dv  = val - mu;
        float var = wred_sum(dv * dv) * (1.f / 64.f);
        zb[rl * 68 + lane] = (__bf16)(dv * rsqrtf(var + 1e-5f) * g[lane] + bln[lane]);
    }
    __syncthreads();

    // ---- GEMM1: z(16x64) @ fc1^T -> relu -> ab16; wave wid: j-tiles 4w..4w+3
    bf16x8 a0 = *(const bf16x8*)&zb[m16 * 68 + q4 * 8];
    bf16x8 a1 = *(const bf16x8*)&zb[m16 * 68 + 32 + q4 * 8];
#pragma unroll
    for (int jt2 = 0; jt2 < 4; ++jt2) {
        int j0t = (wid * 4 + jt2) * 16;
        const __bf16* bp = fc1b16 + (size_t)(j0t + m16) * 64 + q4 * 8;
        f32x4 c = {0.f, 0.f, 0.f, 0.f};
        c = __builtin_amdgcn_mfma_f32_16x16x32_bf16(a0, *(const bf16x8*)bp, c, 0, 0, 0);
        c = __builtin_amdgcn_mfma_f32_16x16x32_bf16(a1, *(const bf16x8*)(bp + 32), c, 0, 0, 0);
        int j = j0t + m16;
        float bias = fc1b[j];
#pragma unroll
        for (int r = 0; r < 4; ++r)
            ab[(q4 * 4 + r) * 264 + j] = (__bf16)fmaxf(c[r] + bias, 0.f);
    }
    __syncthreads();

    // ---- GEMM2: a(16x256) @ fc2^T; wave wid: d-cols 16w..16w+15 ----
    f32x4 c2a = {0.f, 0.f, 0.f, 0.f}, c2b = {0.f, 0.f, 0.f, 0.f};
    const __bf16* b2p = fc2b16 + (size_t)(wid * 16 + m16) * 256 + q4 * 8;
#pragma unroll
    for (int k8 = 0; k8 < 8; k8 += 2) {
        bf16x8 aa0 = *(const bf16x8*)&ab[m16 * 264 + k8 * 32 + q4 * 8];
        bf16x8 aa1 = *(const bf16x8*)&ab[m16 * 264 + (k8 + 1) * 32 + q4 * 8];
        c2a = __builtin_amdgcn_mfma_f32_16x16x32_bf16(aa0, *(const bf16x8*)(b2p + k8 * 32), c2a, 0, 0, 0);
        c2b = __builtin_amdgcn_mfma_f32_16x16x32_bf16(aa1, *(const bf16x8*)(b2p + (k8 + 1) * 32), c2b, 0, 0, 0);
    }
    int d = wid * 16 + m16;
    float bias2 = fc2b[d];
#pragma unroll
    for (int r = 0; r < 4; ++r) {
        size_t row = (size_t)(r0 + q4 * 4 + r);
        out[row * 64 + d] = h[row * 64 + d] + c2a[r] + c2b[r] + bias2;
    }
}

extern "C" void kernel_launch(void* const* d_in, const int* in_sizes, int n_in,
                              void* d_out, int out_size, void* d_ws, size_t ws_size,
                              hipStream_t stream) {
    const float* x    = (const float*)d_in[0];
    const float* stg  = (const float*)d_in[1];
    const int*   topk = (const int*)d_in[2];
    const float* qw   = (const float*)d_in[3];
    const float* qb   = (const float*)d_in[4];
    const float* kw   = (const float*)d_in[5];
    const float* kb   = (const float*)d_in[6];
    const float* lng  = (const float*)d_in[7];
    const float* lnb  = (const float*)d_in[8];
    const float* flng = (const float*)d_in[9];
    const float* flnb = (const float*)d_in[10];
    const float* fc1w = (const float*)d_in[11];
    const float* fc1b = (const float*)d_in[12];
    const float* fc2w = (const float*)d_in[13];
    const float* fc2b = (const float*)d_in[14];
    float* out = (float*)d_out;

    // Workspace layout (float units), ~55 MB total
    float* ws = (float*)d_ws;
    __bf16* xnb = (__bf16*)ws;                 // ROWSX*64 bf16 = 1,886,208 f
    float* p1   = ws + 1886208;
    __bf16* xnT = (__bf16*)p1;                 // 16*64*3840 bf16 = 1,966,080 f
    float* p2   = p1 + 1966080;
    __bf16* qtb = (__bf16*)p2;                 // 4928*64 bf16 = 157,696 f
    float* y32  = p2 + 157696;                 // 314,368 f
    float* cq   = y32 + 314368;                // 4,928 f
    float* M    = cq + 4928;                   // 4,096
    float* b2   = M + 4096;                    // 64
    float* vv   = b2 + 64;                     // 64
    float* cc   = vv + 64;                     // 16
    __bf16* fc1b16 = (__bf16*)(cc + 16);       // 16384 bf16 = 8,192 f
    __bf16* fc2b16 = (__bf16*)((float*)fc1b16 + 8192);  // 8,192 f
    __bf16* sag = (__bf16*)((float*)fc2b16 + 8192);     // ROWSH*3712 bf16 = 9,116,672 f
    float* h    = (float*)sag + 9116672;       // 314,368 f

    fold_k<<<64, 64, 0, stream>>>(qw, qb, kw, kb, M, b2, vv, cc);
    wconv_k<<<128, 256, 0, stream>>>(fc1w, fc2w, fc1b16, fc2b16);
    ln_k<<<(ROWSX + 3) / 4, 256, 0, stream>>>(x, lng, lnb, xnb, y32);
    t_k<<<dim3((TN + 63) / 64, BB), 256, 0, stream>>>(xnb, xnT);
    qt_k<<<(ROWSH + 3) / 4, 256, 0, stream>>>(y32, M, b2, vv, cc, qtb, cq);
    score_k<<<dim3((TN + 127) / 128, (NN + 63) / 64, BB), 256, 0, stream>>>(qtb, cq, xnb, stg, sag);
    attn_k<<<dim3((NN + 3) / 4, BB), 256, 0, stream>>>(sag, xnT, y32, topk, h);
    ffn_k<<<ROWSH / 16, 256, 0, stream>>>(h, flng, flnb, fc1b16, fc1b, fc2b16, fc2b, out);
}

// Round 8
// 273.647 us; speedup vs baseline: 1.4778x; 1.0831x over previous
//
#include <hip/hip_runtime.h>

typedef __bf16 bf16x8 __attribute__((ext_vector_type(8)));
typedef float  f32x4  __attribute__((ext_vector_type(4)));
typedef unsigned short u16x8 __attribute__((ext_vector_type(8)));

// Problem constants
constexpr int BB    = 16;
constexpr int TT    = 12;
constexpr int NN    = 307;
constexpr int TN    = TT * NN;        // 3684
constexpr int ROWSX = BB * TT * NN;   // 58944
constexpr int ROWSH = BB * NN;        // 4912
constexpr int SST1  = 3712;           // sag row stride (464 x b128 chunks)
constexpr int SSTR  = 3840;           // xnT row stride
constexpr float SCALE = 0.125f;

__device__ __forceinline__ float wred_sum(float v) {
#pragma unroll
    for (int m = 32; m > 0; m >>= 1) v += __shfl_xor(v, m, 64);
    return v;
}

// ---------------------------------------------------------------------------
// Fold q/k projections: dg = q.k = qt.x_ + c
// ---------------------------------------------------------------------------
__global__ void fold_k(const float* __restrict__ qw, const float* __restrict__ qb,
                       const float* __restrict__ kw, const float* __restrict__ kb,
                       float* __restrict__ M, float* __restrict__ b2,
                       float* __restrict__ vv, float* __restrict__ cc) {
    int e = blockIdx.x, d = threadIdx.x;
    float acc = 0.f;
    for (int dp = 0; dp < 64; ++dp) acc += qw[dp * 64 + e] * kw[dp * 64 + d];
    M[e * 64 + d] = acc;
    float vp = wred_sum(qw[d * 64 + e] * kb[d]);
    if (d == 0) vv[e] = vp;
    if (e == 0) {
        float b = 0.f;
        for (int dp = 0; dp < 64; ++dp) b += qb[dp] * kw[dp * 64 + d];
        b2[d] = b;
        float cp = wred_sum(qb[d] * kb[d]);
        if (d == 0) *cc = cp;
    }
}

// ---------------------------------------------------------------------------
// fc1w/fc2w fp32 -> bf16
// ---------------------------------------------------------------------------
__global__ void wconv_k(const float* __restrict__ fc1w, const float* __restrict__ fc2w,
                        __bf16* __restrict__ fc1b16, __bf16* __restrict__ fc2b16) {
    int i = blockIdx.x * 256 + threadIdx.x;
    if (i < 16384) fc1b16[i] = (__bf16)fc1w[i];
    else fc2b16[i - 16384] = (__bf16)fc2w[i - 16384];
}

// ---------------------------------------------------------------------------
// LayerNorm -> xnb (bf16) + y32 (fp32, t==11 slab)
// ---------------------------------------------------------------------------
__global__ __launch_bounds__(256) void ln_k(const float* __restrict__ x,
                                            const float* __restrict__ g,
                                            const float* __restrict__ b,
                                            __bf16* __restrict__ xnb,
                                            float* __restrict__ y32) {
    int w = threadIdx.x >> 6, l = threadIdx.x & 63;
    int r = blockIdx.x * 4 + w;
    if (r >= ROWSX) return;
    float val = x[r * 64 + l];
    float mu  = wred_sum(val) * (1.f / 64.f);
    float dv  = val - mu;
    float var = wred_sum(dv * dv) * (1.f / 64.f);
    float xv  = dv * rsqrtf(var + 1e-5f) * g[l] + b[l];
    xnb[(size_t)r * 64 + l] = (__bf16)xv;
    int t = (r / NN) % TT;
    if (t == TT - 1) {
        int bbv = r / (NN * TT), n = r % NN;
        y32[(bbv * NN + n) * 64 + l] = xv;
    }
}

// ---------------------------------------------------------------------------
// Transpose xnb[b,j,d] -> xnT[b,d,j] (stride SSTR; j>=TN zero within tiles)
// ---------------------------------------------------------------------------
__global__ __launch_bounds__(256) void t_k(const __bf16* __restrict__ xnb,
                                           __bf16* __restrict__ xnT) {
    __shared__ unsigned short tile[64][65];
    int bb = blockIdx.y, j0 = blockIdx.x * 64, t = threadIdx.x;
    const unsigned short* src = (const unsigned short*)xnb;
    unsigned short* dst = (unsigned short*)xnT;
#pragma unroll
    for (int i = 0; i < 16; ++i) {
        int f = t + 256 * i, jr = f >> 6, dc = f & 63;
        int j = j0 + jr;
        tile[jr][dc] = (j < TN) ? src[((size_t)bb * TN + j) * 64 + dc] : (unsigned short)0;
    }
    __syncthreads();
#pragma unroll
    for (int i = 0; i < 16; ++i) {
        int f = t + 256 * i, d = f >> 6, jj = f & 63;
        dst[((size_t)bb * 64 + d) * SSTR + j0 + jj] = tile[jj][d];
    }
}

// ---------------------------------------------------------------------------
// qt[row] = y_ @ M + b2 (bf16);  cq[row] = y_.v + cc
// ---------------------------------------------------------------------------
__global__ __launch_bounds__(256) void qt_k(const float* __restrict__ y32,
                                            const float* __restrict__ M,
                                            const float* __restrict__ b2,
                                            const float* __restrict__ vv,
                                            const float* __restrict__ ccp,
                                            __bf16* __restrict__ qtb,
                                            float* __restrict__ cq) {
    int w = threadIdx.x >> 6, l = threadIdx.x & 63;
    int rr = blockIdx.x * 4 + w;
    if (rr >= ROWSH) return;
    float y = y32[rr * 64 + l];
    float acc = b2[l];
#pragma unroll
    for (int e = 0; e < 64; ++e) acc += __shfl(y, e, 64) * M[e * 64 + l];
    qtb[(size_t)rr * 64 + l] = (__bf16)acc;
    float cp = wred_sum(y * vv[l]);
    if (l == 0) cq[rr] = cp + *ccp;
}

// ---------------------------------------------------------------------------
// Score GEMM via MFMA. stg staged via LDS float4. Epilogue computes bf16
// weights into registers, transposes through LDS (overlaying sstg), then
// stores coalesced b128 (was: 8192 scattered 2B stores per block).
// ---------------------------------------------------------------------------
__global__ __launch_bounds__(256) void score_k(const __bf16* __restrict__ qtb,
                                               const float* __restrict__ cq,
                                               const __bf16* __restrict__ xnb,
                                               const float* __restrict__ stg,
                                               __bf16* __restrict__ sag) {
    __shared__ float sstg[64 * 132];   // 33 KB; phase-2 overlay: u16 wb[64][136]
    int bb = blockIdx.z, n0 = blockIdx.y * 64, j0 = blockIdx.x * 128;
    int t = threadIdx.x;
    int w = t >> 6, lane = t & 63;
    int m16 = lane & 15, q4 = lane >> 4;

    // ---- stage stg tile [64n x 128j] fp32 -> LDS (coalesced float4) ----
#pragma unroll
    for (int i = 0; i < 8; ++i) {
        int flat = t + i * 256;
        int row = flat >> 5, c4 = (flat & 31) * 4;
        int n = n0 + row;
        float4 v = {0.f, 0.f, 0.f, 0.f};
        if (n < NN) {
            size_t rb = (size_t)(bb * NN + n) * TN;
            int j = j0 + c4;
            if (j + 3 < TN) v = *(const float4*)(stg + rb + j);
            else {
                if (j + 0 < TN) v.x = stg[rb + j + 0];
                if (j + 1 < TN) v.y = stg[rb + j + 1];
                if (j + 2 < TN) v.z = stg[rb + j + 2];
                if (j + 3 < TN) v.w = stg[rb + j + 3];
            }
        }
        *(float4*)&sstg[row * 132 + c4] = v;
    }

    // ---- MFMA: 64n x 128j, K=64 ----
    const bf16x8* ap = (const bf16x8*)(qtb + ((size_t)bb * NN + n0 + w * 16 + m16) * 64);
    bf16x8 a0 = ap[q4], a1 = ap[q4 + 4];
    f32x4 acc[8];
#pragma unroll
    for (int jt = 0; jt < 8; ++jt) {
        const bf16x8* bp = (const bf16x8*)(xnb + ((size_t)bb * TN + j0 + jt * 16 + m16) * 64);
        bf16x8 b0 = bp[q4], b1 = bp[q4 + 4];
        f32x4 c = {0.f, 0.f, 0.f, 0.f};
        c = __builtin_amdgcn_mfma_f32_16x16x32_bf16(a0, b0, c, 0, 0, 0);
        c = __builtin_amdgcn_mfma_f32_16x16x32_bf16(a1, b1, c, 0, 0, 0);
        acc[jt] = c;
    }
    int nbase = n0 + w * 16 + q4 * 4;
    float cn[4];
#pragma unroll
    for (int r = 0; r < 4; ++r) {
        int n = nbase + r;
        cn[r] = (n < NN) ? cq[bb * NN + n] : 0.f;
    }
    __syncthreads();

    // ---- epilogue phase 1: compute bf16 weights into registers ----
    u16x8 wvr[4];
#pragma unroll
    for (int r = 0; r < 4; ++r) {
        int nloc = w * 16 + q4 * 4 + r;
#pragma unroll
        for (int jt = 0; jt < 8; ++jt) {
            int j = j0 + jt * 16 + m16;
            float sv = sstg[nloc * 132 + jt * 16 + m16];
            float dg = (acc[jt][r] + cn[r]) * SCALE;
            float s  = 1.f / (1.f + __expf(-dg));
            float wv = (j < TN) ? s * sv * SCALE : 0.f;
            __bf16 wb16 = (__bf16)wv;
            wvr[r][jt] = *(unsigned short*)&wb16;
        }
    }
    __syncthreads();   // all sstg reads done -> safe to overlay

    // ---- phase 2: scatter u16 to LDS (2-way aliasing only = free) ----
    unsigned short* wb = (unsigned short*)sstg;   // stride 136
#pragma unroll
    for (int r = 0; r < 4; ++r) {
        int nloc = w * 16 + q4 * 4 + r;
#pragma unroll
        for (int jt = 0; jt < 8; ++jt)
            wb[nloc * 136 + jt * 16 + m16] = wvr[r][jt];
    }
    __syncthreads();

    // ---- phase 3: coalesced b128 stores ----
#pragma unroll
    for (int i = 0; i < 4; ++i) {
        int chunk = t + i * 256;          // 0..1023
        int row = chunk >> 4, c8 = (chunk & 15) * 8;
        int n = n0 + row;
        if (n < NN) {
            u16x8 v = *(const u16x8*)&wb[row * 136 + c8];
            *(u16x8*)((unsigned short*)sag + (size_t)(bb * NN + n) * SST1 + j0 + c8) = v;
        }
    }
}

// ---------------------------------------------------------------------------
// attn v3: 8 rows/block (512 thr, 8 waves, one row per wave).
// Ballot-count binary search (no DS shuffle chains). PV d-split(4) x
// K-split(2), LDS pair-reduce. LDS 61.6 KB -> 2 blocks/CU = 16 waves/CU.
// ---------------------------------------------------------------------------
__global__ __launch_bounds__(512) void attn_k(const __bf16* __restrict__ sagB,
                                              const __bf16* __restrict__ xnT,
                                              const float* __restrict__ y32,
                                              const int* __restrict__ topk_p,
                                              float* __restrict__ h) {
    __shared__ unsigned short sg[8][3720];   // 59.5 KB
    __shared__ float red[4][8][16];          // 2 KB (K-split partials)
    int t = threadIdx.x;
    int bb = blockIdx.y, n0 = blockIdx.x * 8;
    int wid = t >> 6, lane = t & 63;
    int m16 = lane & 15, q4 = lane >> 4;

    int topkv = *topk_p;
    bool selAll = (topkv <= 0);
    int kk = 0;
    if (!selAll) {
        kk = (topkv < 5) ? topkv * NN : topkv;
        if (kk > TN) kk = TN;
    }

    // ---- wave wid owns row n0+wid ----
    int n = n0 + wid;
    const u16x8* src = (const u16x8*)((const unsigned short*)sagB +
                                      (size_t)(bb * NN + min(n, NN - 1)) * SST1);
    u16x8 va[8];
#pragma unroll
    for (int ci = 0; ci < 8; ++ci) {
        int c = lane + (ci << 6);
        u16x8 v = {0, 0, 0, 0, 0, 0, 0, 0};
        if (c < 464) v = src[c];
        va[ci] = v;
    }
    // row max (values >= 0; bf16 bit order = value order; pads 0)
    int vmb = 0;
#pragma unroll
    for (int ci = 0; ci < 8; ++ci)
#pragma unroll
        for (int e = 0; e < 8; ++e) vmb = max(vmb, (int)va[ci][e]);
#pragma unroll
    for (int m = 32; m > 0; m >>= 1) vmb = max(vmb, __shfl_xor(vmb, m, 64));
    float vmax = __uint_as_float(((unsigned)vmb) << 16);

    // exact kk-th largest: smallest T with cnt(>T) < kk.
    // count via ballot+popcount: wave-uniform, no shuffle chains.
    unsigned thrb = 0;
    if (!selAll) {
        unsigned lo = 0, hi = (unsigned)vmb;
        while (lo < hi) {
            unsigned mid = (lo + hi) >> 1;
            int cnt = 0;
#pragma unroll
            for (int ci = 0; ci < 8; ++ci)
#pragma unroll
                for (int e = 0; e < 8; ++e)
                    cnt += (int)__popcll(__ballot((unsigned)va[ci][e] > mid));
            if (cnt < kk) hi = mid; else lo = mid + 1;
        }
        thrb = lo;
    }

    // softmax sum over selected (cache exp as bf16 in-place)
    float local = 0.f;
#pragma unroll
    for (int ci = 0; ci < 8; ++ci) {
        int c = lane + (ci << 6);
        int nvv = (c < 460) ? 8 : ((c == 460) ? 4 : 0);
#pragma unroll
        for (int e = 0; e < 8; ++e) {
            unsigned u = va[ci][e];
            bool sel = selAll ? (e < nvv) : (u > thrb);
            float ev = sel ? __expf(__uint_as_float(u << 16) - vmax) : 0.f;
            local += ev;
            __bf16 eb = (__bf16)ev;
            va[ci][e] = *(unsigned short*)&eb;
        }
    }
    local = wred_sum(local);
    bool uni = !(local > 0.f);
    float inv = uni ? 0.f : 1.f / local;
    float uval = 1.f / (float)TN;
#pragma unroll
    for (int ci = 0; ci < 8; ++ci) {
        int c = lane + (ci << 6);
        if (c < 464) {
            int nvv = (c < 460) ? 8 : ((c == 460) ? 4 : 0);
            bf16x8 o;
#pragma unroll
            for (int e = 0; e < 8; ++e) {
                if (uni) o[e] = (e < nvv) ? (__bf16)uval : (__bf16)0.f;
                else {
                    unsigned short us = va[ci][e];
                    float ev = (float)(*(__bf16*)&us);
                    o[e] = (__bf16)(ev * inv);
                }
            }
            *(bf16x8*)&sg[wid][c * 8] = o;
        }
    }
    __syncthreads();

    // ---- PV: wave = (dgroup, khalf). A rows 0..7, K 2x1856 ----
    int dg = wid & 3, kh = wid >> 2;
    bf16x8 zf;
#pragma unroll
    for (int e = 0; e < 8; ++e) zf[e] = (__bf16)0.f;
    f32x4 acc0 = {0.f, 0.f, 0.f, 0.f}, acc1 = {0.f, 0.f, 0.f, 0.f};
    const __bf16* bbase = xnT + ((size_t)bb * 64 + dg * 16 + m16) * SSTR + q4 * 8;
    int kbeg = kh * 1856;
    for (int ks = 0; ks < 58; ks += 2) {
        int k0 = kbeg + ks * 32, k1 = k0 + 32;
        bf16x8 a0 = (m16 < 8) ? *(const bf16x8*)&sg[m16][k0 + q4 * 8] : zf;
        bf16x8 a1 = (m16 < 8) ? *(const bf16x8*)&sg[m16][k1 + q4 * 8] : zf;
        bf16x8 b0 = *(const bf16x8*)(bbase + k0);
        bf16x8 b1 = *(const bf16x8*)(bbase + k1);
        acc0 = __builtin_amdgcn_mfma_f32_16x16x32_bf16(a0, b0, acc0, 0, 0, 0);
        acc1 = __builtin_amdgcn_mfma_f32_16x16x32_bf16(a1, b1, acc1, 0, 0, 0);
    }
    // C rows 0..7 live in quads 0,1 (row = q4*4+r, col = m16)
    if (kh == 0) {
        if (q4 < 2) {
#pragma unroll
            for (int r = 0; r < 4; ++r)
                red[dg][q4 * 4 + r][m16] = acc0[r] + acc1[r];
        }
    }
    __syncthreads();
    if (kh == 1 && q4 < 2) {
#pragma unroll
        for (int r = 0; r < 4; ++r) {
            int row = q4 * 4 + r;
            int nn2 = n0 + row;
            if (nn2 < NN) {
                size_t o = (size_t)(bb * NN + nn2) * 64 + dg * 16 + m16;
                h[o] = acc0[r] + acc1[r] + red[dg][row][m16] + y32[o];
            }
        }
    }
}

// ---------------------------------------------------------------------------
// FFN via MFMA bf16: LN -> zb16(LDS) -> @fc1^T+relu -> ab16(LDS)
// -> @fc2^T + h + b. 16 rows/block, LDS ~11 KB.
// ---------------------------------------------------------------------------
__global__ __launch_bounds__(256) void ffn_k(const float* __restrict__ h,
                                             const float* __restrict__ g,
                                             const float* __restrict__ bln,
                                             const __bf16* __restrict__ fc1b16,
                                             const float* __restrict__ fc1b,
                                             const __bf16* __restrict__ fc2b16,
                                             const float* __restrict__ fc2b,
                                             float* __restrict__ out) {
    __shared__ __bf16 zb[16 * 68];
    __shared__ __bf16 ab[16 * 264];
    int t = threadIdx.x, r0 = blockIdx.x * 16;
    int wid = t >> 6, lane = t & 63;
    int m16 = lane & 15, q4 = lane >> 4;

#pragma unroll
    for (int q = 0; q < 4; ++q) {
        int rl = wid * 4 + q;
        float val = h[(size_t)(r0 + rl) * 64 + lane];
        float mu  = wred_sum(val) * (1.f / 64.f);
        float dv  = val - mu;
        float var = wred_sum(dv * dv) * (1.f / 64.f);
        zb[rl * 68 + lane] = (__bf16)(dv * rsqrtf(var + 1e-5f) * g[lane] + bln[lane]);
    }
    __syncthreads();

    bf16x8 a0 = *(const bf16x8*)&zb[m16 * 68 + q4 * 8];
    bf16x8 a1 = *(const bf16x8*)&zb[m16 * 68 + 32 + q4 * 8];
#pragma unroll
    for (int jt2 = 0; jt2 < 4; ++jt2) {
        int j0t = (wid * 4 + jt2) * 16;
        const __bf16* bp = fc1b16 + (size_t)(j0t + m16) * 64 + q4 * 8;
        f32x4 c = {0.f, 0.f, 0.f, 0.f};
        c = __builtin_amdgcn_mfma_f32_16x16x32_bf16(a0, *(const bf16x8*)bp, c, 0, 0, 0);
        c = __builtin_amdgcn_mfma_f32_16x16x32_bf16(a1, *(const bf16x8*)(bp + 32), c, 0, 0, 0);
        int j = j0t + m16;
        float bias = fc1b[j];
#pragma unroll
        for (int r = 0; r < 4; ++r)
            ab[(q4 * 4 + r) * 264 + j] = (__bf16)fmaxf(c[r] + bias, 0.f);
    }
    __syncthreads();

    f32x4 c2a = {0.f, 0.f, 0.f, 0.f}, c2b = {0.f, 0.f, 0.f, 0.f};
    const __bf16* b2p = fc2b16 + (size_t)(wid * 16 + m16) * 256 + q4 * 8;
#pragma unroll
    for (int k8 = 0; k8 < 8; k8 += 2) {
        bf16x8 aa0 = *(const bf16x8*)&ab[m16 * 264 + k8 * 32 + q4 * 8];
        bf16x8 aa1 = *(const bf16x8*)&ab[m16 * 264 + (k8 + 1) * 32 + q4 * 8];
        c2a = __builtin_amdgcn_mfma_f32_16x16x32_bf16(aa0, *(const bf16x8*)(b2p + k8 * 32), c2a, 0, 0, 0);
        c2b = __builtin_amdgcn_mfma_f32_16x16x32_bf16(aa1, *(const bf16x8*)(b2p + (k8 + 1) * 32), c2b, 0, 0, 0);
    }
    int d = wid * 16 + m16;
    float bias2 = fc2b[d];
#pragma unroll
    for (int r = 0; r < 4; ++r) {
        size_t row = (size_t)(r0 + q4 * 4 + r);
        out[row * 64 + d] = h[row * 64 + d] + c2a[r] + c2b[r] + bias2;
    }
}

extern "C" void kernel_launch(void* const* d_in, const int* in_sizes, int n_in,
                              void* d_out, int out_size, void* d_ws, size_t ws_size,
                              hipStream_t stream) {
    const float* x    = (const float*)d_in[0];
    const float* stg  = (const float*)d_in[1];
    const int*   topk = (const int*)d_in[2];
    const float* qw   = (const float*)d_in[3];
    const float* qb   = (const float*)d_in[4];
    const float* kw   = (const float*)d_in[5];
    const float* kb   = (const float*)d_in[6];
    const float* lng  = (const float*)d_in[7];
    const float* lnb  = (const float*)d_in[8];
    const float* flng = (const float*)d_in[9];
    const float* flnb = (const float*)d_in[10];
    const float* fc1w = (const float*)d_in[11];
    const float* fc1b = (const float*)d_in[12];
    const float* fc2w = (const float*)d_in[13];
    const float* fc2b = (const float*)d_in[14];
    float* out = (float*)d_out;

    float* ws = (float*)d_ws;
    __bf16* xnb = (__bf16*)ws;                 // ROWSX*64 bf16 = 1,886,208 f
    float* p1   = ws + 1886208;
    __bf16* xnT = (__bf16*)p1;                 // 16*64*3840 bf16 = 1,966,080 f
    float* p2   = p1 + 1966080;
    __bf16* qtb = (__bf16*)p2;                 // 4928*64 bf16 = 157,696 f
    float* y32  = p2 + 157696;                 // 314,368 f
    float* cq   = y32 + 314368;                // 4,928 f
    float* M    = cq + 4928;                   // 4,096
    float* b2   = M + 4096;                    // 64
    float* vv   = b2 + 64;                     // 64
    float* cc   = vv + 64;                     // 16
    __bf16* fc1b16 = (__bf16*)(cc + 16);       // 8,192 f
    __bf16* fc2b16 = (__bf16*)((float*)fc1b16 + 8192);  // 8,192 f
    __bf16* sag = (__bf16*)((float*)fc2b16 + 8192);     // ROWSH*3712 bf16 = 9,116,672 f
    float* h    = (float*)sag + 9116672;       // 314,368 f

    fold_k<<<64, 64, 0, stream>>>(qw, qb, kw, kb, M, b2, vv, cc);
    wconv_k<<<128, 256, 0, stream>>>(fc1w, fc2w, fc1b16, fc2b16);
    ln_k<<<(ROWSX + 3) / 4, 256, 0, stream>>>(x, lng, lnb, xnb, y32);
    t_k<<<dim3((TN + 63) / 64, BB), 256, 0, stream>>>(xnb, xnT);
    qt_k<<<(ROWSH + 3) / 4, 256, 0, stream>>>(y32, M, b2, vv, cc, qtb, cq);
    score_k<<<dim3((TN + 127) / 128, (NN + 63) / 64, BB), 256, 0, stream>>>(qtb, cq, xnb, stg, sag);
    attn_k<<<dim3((NN + 7) / 8, BB), 512, 0, stream>>>(sag, xnT, y32, topk, h);
    ffn_k<<<ROWSH / 16, 256, 0, stream>>>(h, flng, flnb, fc1b16, fc1b, fc2b16, fc2b, out);
}